// Round 9
// baseline (305.921 us; speedup 1.0000x reference)
//
#include <hip/hip_runtime.h>
#include <hip/hip_bf16.h>

typedef __attribute__((ext_vector_type(8))) short short8;
typedef __attribute__((ext_vector_type(4))) float floatx4;

#define N_ROWS 32768
#define D_DIM  128
#define H_KEYS 8192
#define C_COLS 100
#define BM     64
#define BH     128
#define P_STRIDE  136   // ushorts per P row (272 B, 16B-aligned rows)
#define P_BYTES   (BM * P_STRIDE * 2)   // 17408 B per buffer
#define OL_STRIDE 113   // floats per OL row (odd -> conflict-free epilogue)
#define LOG2E 1.4426950408889634f

__device__ __forceinline__ unsigned short f2bf(float f) {
  union { float f; unsigned int u; } v; v.f = f;
  unsigned int r = v.u + 0x7fffu + ((v.u >> 16) & 1u);  // RNE
  return (unsigned short)(r >> 16);
}

// v_cvt_pk_bf16_f32: two fp32 -> packed bf16 (a in low 16, b in high 16)
__device__ __forceinline__ unsigned int pk2bf(float a, float b) {
  union { __hip_bfloat162 h; unsigned int u; } c;
  c.h = __float22bfloat162_rn(float2{a, b});
  return c.u;
}

// ---------------------------------------------------------------------------
// pack_all: single-launch fusion of the three preprocessing passes
// (verbatim round-0 logic, harness-verified three times).
//   blocks [0,512):    pack_k — K fp32 -> MFMA A-frag order, scaled 2*log2e/T
//   blocks [512,768):  pack_v — V -> PV B-frag order, 112 cols, ones at 100
//   blocks [768,2816): ksq    — ksq[h] = -|k_h|^2 * log2e / T (1 wave/key)
// ---------------------------------------------------------------------------
__global__ __launch_bounds__(256) void pack_all(const float* __restrict__ keys,
                                                const float* __restrict__ values,
                                                const float* __restrict__ temp,
                                                unsigned short* __restrict__ kp,
                                                unsigned short* __restrict__ vp,
                                                float* __restrict__ ksq) {
  const int bid = blockIdx.x;
  if (bid < 512) {
    int gid = bid * 256 + threadIdx.x;
    int lane = gid & 63;
    int c = (gid >> 6) & 3;
    int rt = gid >> 8;
    float scale = 2.0f * LOG2E / temp[0];
    int row = rt * 16 + (lane & 15);
    int d0 = c * 32 + (lane >> 4) * 8;
    const float* s = keys + (size_t)row * D_DIM + d0;
    short8 o;
#pragma unroll
    for (int j = 0; j < 8; ++j) o[j] = (short)f2bf(s[j] * scale);
    *(short8*)(kp + (size_t)gid * 8) = o;
  } else if (bid < 768) {
    __shared__ float vt[32 * 113];
    int g = bid - 512;
    int tid = threadIdx.x;
    for (int idx = tid; idx < 32 * 112; idx += 256) {
      int k = idx / 112, col = idx - k * 112;
      float val;
      if (col < C_COLS) val = values[(size_t)(g * 32 + k) * C_COLS + col];
      else val = (col == C_COLS) ? 1.0f : 0.0f;
      vt[k * 113 + col] = val;
    }
    __syncthreads();
    for (int u = tid; u < 7 * 64; u += 256) {
      int ct = u >> 6, l = u & 63;
      int n0 = l & 15, q = l >> 4;
      short8 o;
#pragma unroll
      for (int j = 0; j < 8; ++j) o[j] = (short)f2bf(vt[(q * 8 + j) * 113 + ct * 16 + n0]);
      *(short8*)(vp + ((size_t)(g * 7 + ct) * 64 + l) * 8) = o;
    }
  } else {
    int wid = ((bid - 768) * 256 + threadIdx.x) >> 6;  // key index
    int lane = threadIdx.x & 63;
    const float2* row = (const float2*)(keys + (size_t)wid * D_DIM);
    float2 v = row[lane];
    float s = v.x * v.x + v.y * v.y;
#pragma unroll
    for (int off = 32; off > 0; off >>= 1) s += __shfl_down(s, off);
    if (lane == 0) ksq[wid] = -s * LOG2E / temp[0];
  }
}

// ---------------------------------------------------------------------------
// attn_rbf_kernel: round-7's 8-wave partition with round-0's codegen.
//   __launch_bounds__(512, 2): VGPR cap 256 -> compiler keeps the kf/vf/ksq
//   prefetch schedule (round 7's (512,4) squeezed it to 64 VGPR and sank the
//   loads into the MFMA chains -> 241us).  kf hoisted up front (kf[2][4])
//   mirroring the round-0 body that compiled to 108 VGPR.
// Partition (bitwise round-0 arithmetic):
//   QK^T: wave w = (rh=w>>2, kq=w&3) computes kt in {2kq,2kq+1} x rt in
//         {2rh,2rh+1} (16 MFMAs; xf[2][4] = 32 VGPR).
//   PV:   wave w owns C-tile ct=w for w<7 (16 MFMAs).
// One barrier/iter, double-buffered P.  2 blocks/CU x 8 waves = 4 waves/SIMD
// (round 7 measured 45% occupancy for this shape).
// ---------------------------------------------------------------------------
__global__ __launch_bounds__(512, 2)
void attn_rbf_kernel(const float* __restrict__ x,
                     const unsigned short* __restrict__ kp,
                     const float* __restrict__ ksq,
                     const unsigned short* __restrict__ vp,
                     float* __restrict__ out) {
  __shared__ __align__(16) char smem[2 * P_BYTES];  // 34816 B; epilogue OL aliases front
  float* OL = (float*)smem;
  float* rden = (float*)(smem + BM * OL_STRIDE * 4);  // 64 floats at +28928

  const int tid = threadIdx.x;
  const int w = tid >> 6;       // wave 0..7
  const int lane = tid & 63;
  const int n0 = lane & 15;
  const int q = lane >> 4;
  const int rh = w >> 2;        // row half 0/1 (rt in {2rh, 2rh+1})
  const int kq = w & 3;         // key quarter (kt in {2kq, 2kq+1})
  const int ct = w;             // PV C-tile (valid for w < 7)
  const bool has_ct = (w < 7);
  const int b = blockIdx.x;     // row block: rows [64b, 64b+64)

  // X B-fragments for this wave's 2 row tiles (rt = 2rh + i)
  short8 xf[2][4];
#pragma unroll
  for (int i = 0; i < 2; ++i)
#pragma unroll
    for (int c = 0; c < 4; ++c) {
      const float* s = x + (size_t)(b * 64 + (2 * rh + i) * 16 + n0) * D_DIM + c * 32 + q * 8;
      float4 lo = *(const float4*)s;
      float4 hi = *(const float4*)(s + 4);
      union { short8 v; unsigned int u[4]; } cv;
      cv.u[0] = pk2bf(lo.x, lo.y);
      cv.u[1] = pk2bf(lo.z, lo.w);
      cv.u[2] = pk2bf(hi.x, hi.y);
      cv.u[3] = pk2bf(hi.z, hi.w);
      xf[i][c] = cv.v;
    }

  floatx4 oacc[4];
#pragma unroll
  for (int rt = 0; rt < 4; ++rt) oacc[rt] = (floatx4){0.f, 0.f, 0.f, 0.f};

  for (int it = 0; it < H_KEYS / BH; ++it) {
    unsigned short* P = (unsigned short*)(smem + (it & 1) * P_BYTES);

    // ---- global prefetch (L2-resident streams), hoisted like round 0 ----
    short8 kf[2][4];
#pragma unroll
    for (int kt = 0; kt < 2; ++kt)
#pragma unroll
      for (int c = 0; c < 4; ++c)
        kf[kt][c] = *(const short8*)(kp + ((size_t)((it * 8 + 2 * kq + kt) * 4 + c) * 64 + lane) * 8);

    floatx4 ksq4[2];
#pragma unroll
    for (int kt = 0; kt < 2; ++kt)
      ksq4[kt] = *(const floatx4*)(ksq + it * BH + (2 * kq + kt) * 16 + q * 4);

    short8 vf[4];
    if (has_ct) {
#pragma unroll
      for (int c = 0; c < 4; ++c)
        vf[c] = *(const short8*)(vp + ((size_t)((it * 4 + c) * 7 + ct) * 64 + lane) * 8);
    }

    // ---- S^T = K . X^T, C initialized to -ksq (folded softmax bias) ----
#pragma unroll
    for (int kt = 0; kt < 2; ++kt) {
      const int ktg = 2 * kq + kt;   // global key tile 0..7 within iter
      floatx4 s[2];
#pragma unroll
      for (int i = 0; i < 2; ++i) s[i] = ksq4[kt];
#pragma unroll
      for (int c = 0; c < 4; ++c)
#pragma unroll
        for (int i = 0; i < 2; ++i)
          s[i] = __builtin_amdgcn_mfma_f32_16x16x32_bf16(kf[kt][c], xf[i][c], s[i], 0, 0, 0);
      // exp2 + packed cvt: 4 keys -> one ds_write_b64
#pragma unroll
      for (int i = 0; i < 2; ++i) {
        uint2 pk;
        pk.x = pk2bf(__builtin_amdgcn_exp2f(s[i][0]), __builtin_amdgcn_exp2f(s[i][1]));
        pk.y = pk2bf(__builtin_amdgcn_exp2f(s[i][2]), __builtin_amdgcn_exp2f(s[i][3]));
        *(uint2*)(P + ((2 * rh + i) * 16 + n0) * P_STRIDE + ktg * 16 + q * 4) = pk;
      }
    }
    __syncthreads();  // single barrier: P complete; next iter writes the other buffer

    // ---- O += P . V (wave w owns C-tile ct, all 64 rows) ----
    if (has_ct) {
#pragma unroll
      for (int c = 0; c < 4; ++c) {
        short8 pf[4];
#pragma unroll
        for (int rt = 0; rt < 4; ++rt)
          pf[rt] = *(const short8*)(P + (rt * 16 + n0) * P_STRIDE + c * 32 + q * 8);
#pragma unroll
        for (int rt = 0; rt < 4; ++rt)
          oacc[rt] = __builtin_amdgcn_mfma_f32_16x16x32_bf16(pf[rt], vf[c], oacc[rt], 0, 0, 0);
      }
    }
  }
  __syncthreads();  // all waves done reading P before OL overlays it

  // ---- epilogue: O tiles -> LDS fp32, per-row reciprocal, coalesced store ----
  if (has_ct) {
#pragma unroll
    for (int rt = 0; rt < 4; ++rt)
#pragma unroll
      for (int i = 0; i < 4; ++i)
        OL[(rt * 16 + q * 4 + i) * OL_STRIDE + ct * 16 + n0] = oacc[rt][i];
  }
  __syncthreads();
  if (tid < BM) rden[tid] = 1.0f / OL[tid * OL_STRIDE + 100];
  __syncthreads();

  float* outb = out + (size_t)b * (BM * C_COLS);
  for (int idx = tid; idx < BM * C_COLS; idx += 512) {
    int n = idx / C_COLS;
    int cc = idx - n * C_COLS;
    outb[idx] = OL[n * OL_STRIDE + cc] * rden[n];
  }
}

extern "C" void kernel_launch(void* const* d_in, const int* in_sizes, int n_in,
                              void* d_out, int out_size, void* d_ws, size_t ws_size,
                              hipStream_t stream) {
  (void)in_sizes; (void)n_in; (void)out_size; (void)ws_size;
  const float* x      = (const float*)d_in[0];
  const float* keys   = (const float*)d_in[1];
  const float* values = (const float*)d_in[2];
  const float* temp   = (const float*)d_in[3];
  float* out = (float*)d_out;

  char* ws = (char*)d_ws;
  unsigned short* kp  = (unsigned short*)(ws);             // 8192*128*2 = 2097152 B
  unsigned short* vp  = (unsigned short*)(ws + 2097152);   // 8192*112*2 = 1835008 B
  float*          ksq = (float*)(ws + 3932160);            // 8192*4     = 32768 B

  hipLaunchKernelGGL(pack_all,        dim3(2816), dim3(256), 0, stream,
                     keys, values, temp, kp, vp, ksq);
  hipLaunchKernelGGL(attn_rbf_kernel, dim3(512),  dim3(512), 0, stream, x, kp, ksq, vp, out);
}

// Round 10
// 205.582 us; speedup vs baseline: 1.4881x; 1.4881x over previous
//
#include <hip/hip_runtime.h>
#include <hip/hip_bf16.h>

typedef __attribute__((ext_vector_type(8))) short short8;
typedef __attribute__((ext_vector_type(4))) float floatx4;

#define N_ROWS 32768
#define D_DIM  128
#define H_KEYS 8192
#define C_COLS 100
#define BM     64
#define BH     128
#define P_STRIDE  136   // ushorts per P row (272 B, 16B-aligned rows)
#define P_BYTES   (BM * P_STRIDE * 2)   // 17408 B per buffer
#define OL_STRIDE 113   // floats per OL row (odd -> conflict-free epilogue)
#define LOG2E 1.4426950408889634f

__device__ __forceinline__ unsigned short f2bf(float f) {
  union { float f; unsigned int u; } v; v.f = f;
  unsigned int r = v.u + 0x7fffu + ((v.u >> 16) & 1u);  // RNE
  return (unsigned short)(r >> 16);
}

// v_cvt_pk_bf16_f32: two fp32 -> packed bf16 (a in low 16, b in high 16)
__device__ __forceinline__ unsigned int pk2bf(float a, float b) {
  union { __hip_bfloat162 h; unsigned int u; } c;
  c.h = __float22bfloat162_rn(float2{a, b});
  return c.u;
}

// ---------------------------------------------------------------------------
// pack_all: single-launch fusion of the three preprocessing passes
// (verbatim round-0 logic, harness-verified four times).
//   blocks [0,512):    pack_k — K fp32 -> MFMA A-frag order, scaled 2*log2e/T
//   blocks [512,768):  pack_v — V -> PV B-frag order, 112 cols, ones at 100
//   blocks [768,2816): ksq    — ksq[h] = -|k_h|^2 * log2e / T (1 wave/key)
// ---------------------------------------------------------------------------
__global__ __launch_bounds__(256) void pack_all(const float* __restrict__ keys,
                                                const float* __restrict__ values,
                                                const float* __restrict__ temp,
                                                unsigned short* __restrict__ kp,
                                                unsigned short* __restrict__ vp,
                                                float* __restrict__ ksq) {
  const int bid = blockIdx.x;
  if (bid < 512) {
    int gid = bid * 256 + threadIdx.x;
    int lane = gid & 63;
    int c = (gid >> 6) & 3;
    int rt = gid >> 8;
    float scale = 2.0f * LOG2E / temp[0];
    int row = rt * 16 + (lane & 15);
    int d0 = c * 32 + (lane >> 4) * 8;
    const float* s = keys + (size_t)row * D_DIM + d0;
    short8 o;
#pragma unroll
    for (int j = 0; j < 8; ++j) o[j] = (short)f2bf(s[j] * scale);
    *(short8*)(kp + (size_t)gid * 8) = o;
  } else if (bid < 768) {
    __shared__ float vt[32 * 113];
    int g = bid - 512;
    int tid = threadIdx.x;
    for (int idx = tid; idx < 32 * 112; idx += 256) {
      int k = idx / 112, col = idx - k * 112;
      float val;
      if (col < C_COLS) val = values[(size_t)(g * 32 + k) * C_COLS + col];
      else val = (col == C_COLS) ? 1.0f : 0.0f;
      vt[k * 113 + col] = val;
    }
    __syncthreads();
    for (int u = tid; u < 7 * 64; u += 256) {
      int ct = u >> 6, l = u & 63;
      int n0 = l & 15, q = l >> 4;
      short8 o;
#pragma unroll
      for (int j = 0; j < 8; ++j) o[j] = (short)f2bf(vt[(q * 8 + j) * 113 + ct * 16 + n0]);
      *(short8*)(vp + ((size_t)(g * 7 + ct) * 64 + l) * 8) = o;
    }
  } else {
    int wid = ((bid - 768) * 256 + threadIdx.x) >> 6;  // key index
    int lane = threadIdx.x & 63;
    const float2* row = (const float2*)(keys + (size_t)wid * D_DIM);
    float2 v = row[lane];
    float s = v.x * v.x + v.y * v.y;
#pragma unroll
    for (int off = 32; off > 0; off >>= 1) s += __shfl_down(s, off);
    if (lane == 0) ksq[wid] = -s * LOG2E / temp[0];
  }
}

// ---------------------------------------------------------------------------
// attn_rbf_kernel: round-0's verified 256-thread/4-wave configuration with
// PV software-pipelined one iteration deep (T15-style):
//   body(it): load kf/ksq(it), vf(it-1); QK^T(it) [MFMA];
//             4x interleaved chunks { PV(it-1) c-chunk [ds_read+MFMA] ;
//                                     exp/pack/write(it) chunk [VALU+ds_write] };
//             barrier.
// PV(it-1) reads buf[(it-1)&1], P(it) writes buf[it&1]: one barrier/iter
// covers all hazards (same W->B->R ordering as round 0; no global_load_lds).
// s/oacc accumulation orders unchanged -> bitwise-identical output.
// The source interleave gives the in-order issue stream MFMA<->VALU co-issue:
// exp2 (~131k cyc/CU, quarter-rate trans) hides under PV's matrix ops.
// ---------------------------------------------------------------------------
__global__ __launch_bounds__(256, 2)
void attn_rbf_kernel(const float* __restrict__ x,
                     const unsigned short* __restrict__ kp,
                     const float* __restrict__ ksq,
                     const unsigned short* __restrict__ vp,
                     float* __restrict__ out) {
  __shared__ __align__(16) char smem[2 * P_BYTES];  // 34816 B; epilogue OL aliases front
  float* OL = (float*)smem;
  float* rden = (float*)(smem + BM * OL_STRIDE * 4);  // 64 floats at +28928

  const int tid = threadIdx.x;
  const int w = tid >> 6;       // wave 0..3
  const int lane = tid & 63;
  const int n0 = lane & 15;
  const int q = lane >> 4;
  const int b = blockIdx.x;     // row block: rows [64b, 64b+64)

  // Load x rows for this block directly (fp32 row-major), convert to B-fragments.
  short8 xf[4][4];
#pragma unroll
  for (int rt = 0; rt < 4; ++rt)
#pragma unroll
    for (int c = 0; c < 4; ++c) {
      const float* s = x + (size_t)(b * 64 + rt * 16 + n0) * D_DIM + c * 32 + q * 8;
      float4 lo = *(const float4*)s;
      float4 hi = *(const float4*)(s + 4);
      union { short8 v; unsigned int u[4]; } cv;
      cv.u[0] = pk2bf(lo.x, lo.y);
      cv.u[1] = pk2bf(lo.z, lo.w);
      cv.u[2] = pk2bf(hi.x, hi.y);
      cv.u[3] = pk2bf(hi.z, hi.w);
      xf[rt][c] = cv.v;
    }

  floatx4 oacc[4][2];
#pragma unroll
  for (int rt = 0; rt < 4; ++rt)
#pragma unroll
    for (int u = 0; u < 2; ++u)
      oacc[rt][u] = (floatx4){0.f, 0.f, 0.f, 0.f};

  const int nct = (w < 3) ? 2 : 1;  // waves own C-tiles {0,1},{2,3},{4,5},{6}
  const int ct0 = w * 2;

  short8 vf[4][2];

  // vf loader for iteration itv (same addressing as round 0)
  auto load_vf = [&](int itv) {
#pragma unroll
    for (int c = 0; c < 4; ++c)
#pragma unroll
      for (int u = 0; u < 2; ++u)
        if (u < nct)
          vf[c][u] = *(const short8*)(vp + ((size_t)((itv * 4 + c) * 7 + (ct0 + u)) * 64 + lane) * 8);
  };

  // PV c-chunk for iteration itp (reads buf[itp&1]); round-0 addressing/order
  auto pv_chunk = [&](int itp, int c) {
    const unsigned short* Pr = (const unsigned short*)(smem + (itp & 1) * P_BYTES);
    short8 pf[4];
#pragma unroll
    for (int rt = 0; rt < 4; ++rt)
      pf[rt] = *(const short8*)(Pr + (rt * 16 + n0) * P_STRIDE + c * 32 + q * 8);
#pragma unroll
    for (int u = 0; u < 2; ++u)
      if (u < nct)
#pragma unroll
        for (int rt = 0; rt < 4; ++rt)
          oacc[rt][u] = __builtin_amdgcn_mfma_f32_16x16x32_bf16(pf[rt], vf[c][u], oacc[rt][u], 0, 0, 0);
  };

  // body: QK^T(it) then 4 interleaved {PV(it-1,c=g) ; exp/write(it) chunk g}
  auto body = [&](int it, bool withPV) {
    // ---- global prefetch (L2-resident streams) ----
    short8 kf[2][4];
#pragma unroll
    for (int kt = 0; kt < 2; ++kt)
#pragma unroll
      for (int c = 0; c < 4; ++c)
        kf[kt][c] = *(const short8*)(kp + ((size_t)((it * 8 + w * 2 + kt) * 4 + c) * 64 + lane) * 8);

    floatx4 ksq4[2];
#pragma unroll
    for (int kt = 0; kt < 2; ++kt)
      ksq4[kt] = *(const floatx4*)(ksq + it * BH + w * 32 + kt * 16 + q * 4);

    if (withPV) load_vf(it - 1);

    // ---- S^T = K . X^T, C initialized to -ksq (c-ascending chains, as r0) ----
    floatx4 s[2][4];
#pragma unroll
    for (int kt = 0; kt < 2; ++kt)
#pragma unroll
      for (int rt = 0; rt < 4; ++rt) s[kt][rt] = ksq4[kt];
#pragma unroll
    for (int c = 0; c < 4; ++c)
#pragma unroll
      for (int kt = 0; kt < 2; ++kt)
#pragma unroll
        for (int rt = 0; rt < 4; ++rt)
          s[kt][rt] = __builtin_amdgcn_mfma_f32_16x16x32_bf16(kf[kt][c], xf[rt][c], s[kt][rt], 0, 0, 0);

    // ---- interleaved: PV(it-1) c-chunk || exp+pack+write(it) chunk ----
    unsigned short* Pw = (unsigned short*)(smem + (it & 1) * P_BYTES);
#pragma unroll
    for (int g = 0; g < 4; ++g) {
      if (withPV) pv_chunk(it - 1, g);
      const int kt = g >> 1;
      const int rt0 = (g & 1) * 2;
#pragma unroll
      for (int i = 0; i < 2; ++i) {
        const int rt = rt0 + i;
        uint2 pk;
        pk.x = pk2bf(__builtin_amdgcn_exp2f(s[kt][rt][0]), __builtin_amdgcn_exp2f(s[kt][rt][1]));
        pk.y = pk2bf(__builtin_amdgcn_exp2f(s[kt][rt][2]), __builtin_amdgcn_exp2f(s[kt][rt][3]));
        *(uint2*)(Pw + (rt * 16 + n0) * P_STRIDE + w * 32 + kt * 16 + q * 4) = pk;
      }
    }
  };

  // prologue: iteration 0 has no PV predecessor
  body(0, false);
  __syncthreads();

  for (int it = 1; it < H_KEYS / BH; ++it) {
    body(it, true);
    __syncthreads();   // P(it) complete; buf[(it-1)&1] free for overwrite
  }

  // drain: PV for the last iteration
  load_vf(63);
#pragma unroll
  for (int c = 0; c < 4; ++c) pv_chunk(63, c);
  __syncthreads();  // all waves done reading P before OL overlays it

  // ---- epilogue: O tiles -> LDS fp32, per-row reciprocal, coalesced store ----
#pragma unroll
  for (int rt = 0; rt < 4; ++rt)
#pragma unroll
    for (int u = 0; u < 2; ++u)
      if (u < nct)
#pragma unroll
        for (int i = 0; i < 4; ++i)
          OL[(rt * 16 + q * 4 + i) * OL_STRIDE + (ct0 + u) * 16 + n0] = oacc[rt][u][i];
  __syncthreads();
  if (tid < BM) rden[tid] = 1.0f / OL[tid * OL_STRIDE + 100];
  __syncthreads();

  float* outb = out + (size_t)b * (BM * C_COLS);
  for (int idx = tid; idx < BM * C_COLS; idx += 256) {
    int n = idx / C_COLS;
    int cc = idx - n * C_COLS;
    outb[idx] = OL[n * OL_STRIDE + cc] * rden[n];
  }
}

extern "C" void kernel_launch(void* const* d_in, const int* in_sizes, int n_in,
                              void* d_out, int out_size, void* d_ws, size_t ws_size,
                              hipStream_t stream) {
  (void)in_sizes; (void)n_in; (void)out_size; (void)ws_size;
  const float* x      = (const float*)d_in[0];
  const float* keys   = (const float*)d_in[1];
  const float* values = (const float*)d_in[2];
  const float* temp   = (const float*)d_in[3];
  float* out = (float*)d_out;

  char* ws = (char*)d_ws;
  unsigned short* kp  = (unsigned short*)(ws);             // 8192*128*2 = 2097152 B
  unsigned short* vp  = (unsigned short*)(ws + 2097152);   // 8192*112*2 = 1835008 B
  float*          ksq = (float*)(ws + 3932160);            // 8192*4     = 32768 B

  hipLaunchKernelGGL(pack_all,        dim3(2816), dim3(256), 0, stream,
                     keys, values, temp, kp, vp, ksq);
  hipLaunchKernelGGL(attn_rbf_kernel, dim3(512),  dim3(256), 0, stream, x, kp, ksq, vp, out);
}